// Round 8
// baseline (408.652 us; speedup 1.0000x reference)
//
#include <hip/hip_runtime.h>
#include <math.h>

#define D 128
#define GCN_NUM 3
#define HEADS 8
#define HD 16
#define L_SEQ 100
#define LEAKY 0.01f
#define SC_BUCKETS 8
#define SC_CHUNK 2048

typedef __attribute__((ext_vector_type(8))) short short8v;
typedef __attribute__((ext_vector_type(4))) float f32x4;

__device__ __forceinline__ unsigned f2bf(float x) {
  unsigned u = __float_as_uint(x);
  return (u + 0x7FFFu + ((u >> 16) & 1u)) >> 16;
}
__device__ __forceinline__ float bflo2f(unsigned u) { return __uint_as_float(u << 16); }
__device__ __forceinline__ float bfhi2f(unsigned u) { return __uint_as_float(u & 0xFFFF0000u); }

// ---------------- prep: fused f32->bf16 converts + deg init + chunk-counter init ----------------

__global__ void prep(const float* __restrict__ s0, unsigned short* __restrict__ d0, int n0,
                     const float* __restrict__ s1, unsigned short* __restrict__ d1, int n1,
                     const float* __restrict__ s2, unsigned short* __restrict__ d2, int n2,
                     int* __restrict__ deg, int N, int* __restrict__ chunk_ctr) {
  int i = blockIdx.x * blockDim.x + threadIdx.x;
  int n4tot = n0 + n1 + n2;
  if (i < n4tot) {
    const float* s; unsigned short* d; int j;
    if (i < n0)           { s = s0; d = d0; j = i; }
    else if (i < n0 + n1) { s = s1; d = d1; j = i - n0; }
    else                  { s = s2; d = d2; j = i - n0 - n1; }
    float4 v = reinterpret_cast<const float4*>(s)[j];
    uint2 o;
    o.x = f2bf(v.x) | (f2bf(v.y) << 16);
    o.y = f2bf(v.z) | (f2bf(v.w) << 16);
    reinterpret_cast<uint2*>(d)[j] = o;
  } else if (i - n4tot < N) {
    deg[i - n4tot] = 1;  // self-loop
  }
  if (i < SC_BUCKETS) chunk_ctr[i] = 0;
}

// ---------------- graph build ----------------

__global__ void count_deg(const int* __restrict__ e0, const int* __restrict__ e1,
                          int* __restrict__ deg, int E) {
  int stride = gridDim.x * blockDim.x;
  for (int i = blockIdx.x * blockDim.x + threadIdx.x; i < E; i += stride) {
    atomicAdd(&deg[e0[i]], 1);
    atomicAdd(&deg[e1[i]], 1);
  }
}

// ---- parallel exclusive scan over deg (2 kernels; NB <= 64) ----

__global__ __launch_bounds__(1024) void block_sum(const int* __restrict__ deg,
                                                  int* __restrict__ bsum, int n) {
  __shared__ int ws[16];
  int tid = threadIdx.x, lane = tid & 63, wid = tid >> 6;
  int i = blockIdx.x * 1024 + tid;
  int v = (i < n) ? deg[i] : 0;
#pragma unroll
  for (int off = 32; off; off >>= 1) v += __shfl_xor(v, off);
  if (lane == 0) ws[wid] = v;
  __syncthreads();
  if (tid == 0) {
    int s = 0;
#pragma unroll
    for (int k = 0; k < 16; ++k) s += ws[k];
    bsum[blockIdx.x] = s;
  }
}

__global__ __launch_bounds__(1024) void scan_final(
    const int* __restrict__ deg, const int* __restrict__ bsum,
    int* __restrict__ row_ptr, int* __restrict__ cursor, int n, int nb) {
  __shared__ int ws[16];
  __shared__ int prefix_s;
  int tid = threadIdx.x, lane = tid & 63, wid = tid >> 6;
  int i = blockIdx.x * 1024 + tid;
  int v = (i < n) ? deg[i] : 0;
  int x = v;
#pragma unroll
  for (int off = 1; off < 64; off <<= 1) {
    int y = __shfl_up(x, off);
    if (lane >= off) x += y;
  }
  if (lane == 63) ws[wid] = x;
  __syncthreads();
  if (wid == 0) {
    int pv = (lane < blockIdx.x) ? bsum[lane] : 0;
#pragma unroll
    for (int off = 32; off; off >>= 1) pv += __shfl_xor(pv, off);
    if (lane == 0) prefix_s = pv;
    int s = (lane < 16) ? ws[lane] : 0;
#pragma unroll
    for (int off = 1; off < 16; off <<= 1) {
      int y = __shfl_up(s, off);
      if (lane >= off) s += y;
    }
    if (lane < 16) ws[lane] = s;
  }
  __syncthreads();
  int woff = wid ? ws[wid - 1] : 0;
  int prefix = prefix_s;
  if (i < n) {
    int pval = prefix + woff + (x - v);
    row_ptr[i] = pval;
    cursor[i] = pval;
  }
  if (blockIdx.x == nb - 1 && tid == 0) row_ptr[n] = prefix + ws[15];
}

// XCD-local scatter: bucket = PHYSICAL XCC_ID (s_getreg, m09). All writers of a
// bucket are on one XCD by construction -> ecw slice accumulates full lines in
// that XCD's L2. Blocks of one XCD partition the edge scan via an atomic chunk
// counter (dynamic: block->XCD census is unknown a priori).
__global__ __launch_bounds__(256) void scatter_edges_xcc(
    const int* __restrict__ e0, const int* __restrict__ e1,
    const float* __restrict__ dv, const int* __restrict__ deg,
    int* __restrict__ cursor, int* __restrict__ chunk_ctr, uint2* __restrict__ ecw,
    int E, int N, int span) {
  unsigned xcc;
  asm volatile("s_getreg_b32 %0, hwreg(HW_REG_XCC_ID)" : "=s"(xcc));
  int bucket = (int)(xcc & (SC_BUCKETS - 1));
  int rlo = bucket * span;
  int rhi = min(rlo + span, N);
  int total = 2 * E + N;
  int nchunks = (total + SC_CHUNK - 1) / SC_CHUNK;
  __shared__ int chunk_s;
  for (;;) {
    __syncthreads();  // guard chunk_s reads from previous iteration
    if (threadIdx.x == 0) chunk_s = atomicAdd(&chunk_ctr[bucket], 1);
    __syncthreads();
    int ch = chunk_s;
    if (ch >= nchunks) break;
    int base = ch * SC_CHUNK;
    int end = min(base + SC_CHUNK, total);
    for (int i = base + (int)threadIdx.x; i < end; i += 256) {
      int r, c; bool self = false;
      if (i < E)          { r = e0[i];     c = e1[i]; }
      else if (i < 2 * E) { r = e1[i - E]; c = e0[i - E]; }
      else                { r = i - 2 * E; c = r; self = true; }
      if (r < rlo || r >= rhi) continue;
      float d = self ? 0.f : dv[(i < E) ? i : i - E];
      float w = expf(-d * d) * (1.0f / sqrtf((float)deg[r])) * (1.0f / sqrtf((float)deg[c]));
      int pos = atomicAdd(&cursor[r], 1);
      ecw[pos] = make_uint2((unsigned)c, __float_as_uint(w));
    }
  }
}

// ---------------- GCN ----------------

// SpMM: one row per wave, 4 edge-groups of 16 lanes, 2-deep pipeline per group.
__global__ __launch_bounds__(256) void spmm_bf(
    const int* __restrict__ row_ptr, const uint2* __restrict__ ecw,
    const unsigned short* __restrict__ enc, unsigned short* __restrict__ agg, int n) {
  int r = blockIdx.x * 4 + (threadIdx.x >> 6);
  if (r >= n) return;
  int lane = threadIdx.x & 63;
  int g = lane >> 4, t = lane & 15;
  int s = row_ptr[r], e = row_ptr[r + 1];
  float a0 = 0.f, a1 = 0.f, a2 = 0.f, a3 = 0.f, a4 = 0.f, a5 = 0.f, a6 = 0.f, a7 = 0.f;
  int i = s + g;
  uint2 cwA = make_uint2(0u, 0u), cwB = make_uint2(0u, 0u);
  if (i < e) cwA = ecw[i];
  if (i + 4 < e) cwB = ecw[i + 4];
  while (i + 4 < e) {
    uint2 cwC = cwA, cwD = cwB;
    if (i + 8 < e)  cwC = ecw[i + 8];
    if (i + 12 < e) cwD = ecw[i + 12];
    float wA = __uint_as_float(cwA.y), wB = __uint_as_float(cwB.y);
    uint4 uA = *reinterpret_cast<const uint4*>(enc + (size_t)cwA.x * D + t * 8);
    uint4 uB = *reinterpret_cast<const uint4*>(enc + (size_t)cwB.x * D + t * 8);
    a0 = fmaf(wA, bflo2f(uA.x), a0); a1 = fmaf(wA, bfhi2f(uA.x), a1);
    a2 = fmaf(wA, bflo2f(uA.y), a2); a3 = fmaf(wA, bfhi2f(uA.y), a3);
    a4 = fmaf(wA, bflo2f(uA.z), a4); a5 = fmaf(wA, bfhi2f(uA.z), a5);
    a6 = fmaf(wA, bflo2f(uA.w), a6); a7 = fmaf(wA, bfhi2f(uA.w), a7);
    a0 = fmaf(wB, bflo2f(uB.x), a0); a1 = fmaf(wB, bfhi2f(uB.x), a1);
    a2 = fmaf(wB, bflo2f(uB.y), a2); a3 = fmaf(wB, bfhi2f(uB.y), a3);
    a4 = fmaf(wB, bflo2f(uB.z), a4); a5 = fmaf(wB, bfhi2f(uB.z), a5);
    a6 = fmaf(wB, bflo2f(uB.w), a6); a7 = fmaf(wB, bfhi2f(uB.w), a7);
    cwA = cwC; cwB = cwD;
    i += 8;
  }
  if (i < e) {
    float wA = __uint_as_float(cwA.y);
    uint4 uA = *reinterpret_cast<const uint4*>(enc + (size_t)cwA.x * D + t * 8);
    a0 = fmaf(wA, bflo2f(uA.x), a0); a1 = fmaf(wA, bfhi2f(uA.x), a1);
    a2 = fmaf(wA, bflo2f(uA.y), a2); a3 = fmaf(wA, bfhi2f(uA.y), a3);
    a4 = fmaf(wA, bflo2f(uA.z), a4); a5 = fmaf(wA, bfhi2f(uA.z), a5);
    a6 = fmaf(wA, bflo2f(uA.w), a6); a7 = fmaf(wA, bfhi2f(uA.w), a7);
  }
  a0 += __shfl_xor(a0, 16); a0 += __shfl_xor(a0, 32);
  a1 += __shfl_xor(a1, 16); a1 += __shfl_xor(a1, 32);
  a2 += __shfl_xor(a2, 16); a2 += __shfl_xor(a2, 32);
  a3 += __shfl_xor(a3, 16); a3 += __shfl_xor(a3, 32);
  a4 += __shfl_xor(a4, 16); a4 += __shfl_xor(a4, 32);
  a5 += __shfl_xor(a5, 16); a5 += __shfl_xor(a5, 32);
  a6 += __shfl_xor(a6, 16); a6 += __shfl_xor(a6, 32);
  a7 += __shfl_xor(a7, 16); a7 += __shfl_xor(a7, 32);
  if (g == 0) {
    uint4 o;
    o.x = f2bf(a0) | (f2bf(a1) << 16);
    o.y = f2bf(a2) | (f2bf(a3) << 16);
    o.z = f2bf(a4) | (f2bf(a5) << 16);
    o.w = f2bf(a6) | (f2bf(a7) << 16);
    *reinterpret_cast<uint4*>(agg + (size_t)r * D + t * 8) = o;
  }
}

// enc = normalize(leaky_relu(A @ W^T + b)) via MFMA bf16.
__global__ __launch_bounds__(256) void dense_mfma(
    const unsigned short* __restrict__ A, const unsigned short* __restrict__ Wb,
    const float* __restrict__ bias, unsigned short* __restrict__ enc, int n) {
  __shared__ unsigned short Wl[128 * 136];
  int tid = threadIdx.x;
  {
    int cg = (tid & 15) * 8;
    int r0 = tid >> 4;
#pragma unroll
    for (int i = 0; i < 8; ++i) {
      int row = r0 + i * 16;
      *reinterpret_cast<short8v*>(&Wl[row * 136 + cg]) =
          *reinterpret_cast<const short8v*>(Wb + row * D + cg);
    }
  }
  __syncthreads();
  int w = tid >> 6, lane = tid & 63;
  int lr = lane & 15, lg = lane >> 4;
#pragma unroll
  for (int rt = 0; rt < 2; ++rt) {
    int rbase = blockIdx.x * 128 + rt * 64 + w * 16;
    f32x4 acc[8];
#pragma unroll
    for (int j = 0; j < 8; ++j) acc[j] = f32x4{0.f, 0.f, 0.f, 0.f};
    const unsigned short* arow = A + (size_t)(rbase + lr) * D + lg * 8;
#pragma unroll
    for (int ks = 0; ks < 4; ++ks) {
      short8v a = *reinterpret_cast<const short8v*>(arow + ks * 32);
#pragma unroll
      for (int jt = 0; jt < 8; ++jt) {
        short8v b = *reinterpret_cast<const short8v*>(&Wl[(jt * 16 + lr) * 136 + ks * 32 + lg * 8]);
        acc[jt] = __builtin_amdgcn_mfma_f32_16x16x32_bf16(a, b, acc[jt], 0, 0, 0);
      }
    }
    float vals[8][4];
    float ss[4] = {0.f, 0.f, 0.f, 0.f};
#pragma unroll
    for (int jt = 0; jt < 8; ++jt) {
      float bj = bias[jt * 16 + lr];
#pragma unroll
      for (int i = 0; i < 4; ++i) {
        float t = acc[jt][i] + bj;
        t = (t > 0.f) ? t : LEAKY * t;
        vals[jt][i] = t;
        ss[i] += t * t;
      }
    }
#pragma unroll
    for (int i = 0; i < 4; ++i) {
      float s = ss[i];
      s += __shfl_xor(s, 1); s += __shfl_xor(s, 2);
      s += __shfl_xor(s, 4); s += __shfl_xor(s, 8);
      ss[i] = 1.0f / fmaxf(sqrtf(s), 1e-12f);
    }
#pragma unroll
    for (int i = 0; i < 4; ++i) {
      int row = rbase + lg * 4 + i;
      if (row < n) {
#pragma unroll
        for (int jt = 0; jt < 8; ++jt)
          enc[(size_t)row * D + jt * 16 + lr] = (unsigned short)f2bf(vals[jt][i] * ss[i]);
      }
    }
  }
}

// ---------------- gather + attention ----------------

__global__ void gather_tar(const unsigned short* __restrict__ src,
                           const int* __restrict__ poi_idx, float* __restrict__ tar, int B) {
  int j = blockIdx.x;
  if (j < B) {
    int t = threadIdx.x;  // 64 threads
    unsigned u = reinterpret_cast<const unsigned*>(src + (size_t)poi_idx[j] * D)[t];
    reinterpret_cast<float2*>(tar + (size_t)j * D)[t] = make_float2(bflo2f(u), bfhi2f(u));
  }
}

// qkv via MFMA with fused x_idx row gather: A row = enc[x_idx[row]].
__global__ __launch_bounds__(256) void qkv_mfma(
    const unsigned short* __restrict__ enc, const int* __restrict__ x_idx,
    const unsigned short* __restrict__ Wb, const float* __restrict__ bias,
    float* __restrict__ qkv, int M) {
  __shared__ unsigned short Wl[128 * 136];
  int tid = threadIdx.x;
  const unsigned short* Wslab = Wb + (size_t)blockIdx.y * 128 * D;
  {
    int cg = (tid & 15) * 8;
    int r0 = tid >> 4;
#pragma unroll
    for (int i = 0; i < 8; ++i) {
      int row = r0 + i * 16;
      *reinterpret_cast<short8v*>(&Wl[row * 136 + cg]) =
          *reinterpret_cast<const short8v*>(Wslab + row * D + cg);
    }
  }
  __syncthreads();
  int w = tid >> 6, lane = tid & 63;
  int lr = lane & 15, lg = lane >> 4;
  int colbase = blockIdx.y * 128;
#pragma unroll
  for (int rt = 0; rt < 2; ++rt) {
    int rbase = blockIdx.x * 128 + rt * 64 + w * 16;
    f32x4 acc[8];
#pragma unroll
    for (int j = 0; j < 8; ++j) acc[j] = f32x4{0.f, 0.f, 0.f, 0.f};
    const unsigned short* arow = enc + (size_t)x_idx[rbase + lr] * D + lg * 8;
#pragma unroll
    for (int ks = 0; ks < 4; ++ks) {
      short8v a = *reinterpret_cast<const short8v*>(arow + ks * 32);
#pragma unroll
      for (int jt = 0; jt < 8; ++jt) {
        short8v b = *reinterpret_cast<const short8v*>(&Wl[(jt * 16 + lr) * 136 + ks * 32 + lg * 8]);
        acc[jt] = __builtin_amdgcn_mfma_f32_16x16x32_bf16(a, b, acc[jt], 0, 0, 0);
      }
    }
#pragma unroll
    for (int jt = 0; jt < 8; ++jt) {
      int j = colbase + jt * 16 + lr;
      float bj = bias[j];
#pragma unroll
      for (int i = 0; i < 4; ++i) {
        int row = rbase + lg * 4 + i;
        if (row < M) qkv[(size_t)row * 384 + j] = acc[jt][i] + bj;
      }
    }
  }
}

__global__ __launch_bounds__(128) void attn_kernel(
    const float* __restrict__ qkv, float* __restrict__ o) {
  __shared__ float k_s[L_SEQ][HD];
  __shared__ float v_s[L_SEQ][HD];
  __shared__ float sc[L_SEQ][L_SEQ + 1];
  int b = blockIdx.x / HEADS;
  int h = blockIdx.x % HEADS;
  int tid = threadIdx.x;
  const size_t rowbase = (size_t)b * L_SEQ;
  for (int idx = tid; idx < L_SEQ * HD; idx += 128) {
    int l = idx >> 4, d2 = idx & 15;
    const float* base = qkv + (rowbase + l) * 384 + h * HD + d2;
    k_s[l][d2] = base[128];
    v_s[l][d2] = base[256];
  }
  __syncthreads();
  if (tid < L_SEQ) {
    float q[HD];
    const float* qp = qkv + (rowbase + tid) * 384 + h * HD;
#pragma unroll
    for (int d2 = 0; d2 < HD; ++d2) q[d2] = qp[d2];
    float m = -1e30f;
    for (int j = 0; j < L_SEQ; ++j) {
      float s = 0.f;
#pragma unroll
      for (int d2 = 0; d2 < HD; ++d2) s += q[d2] * k_s[j][d2];
      s *= 0.25f;
      sc[tid][j] = s;
      m = fmaxf(m, s);
    }
    float sum = 0.f;
    for (int j = 0; j < L_SEQ; ++j) {
      float e = expf(sc[tid][j] - m);
      sc[tid][j] = e;
      sum += e;
    }
    float inv = 1.f / sum;
    float oacc[HD];
#pragma unroll
    for (int d2 = 0; d2 < HD; ++d2) oacc[d2] = 0.f;
    for (int j = 0; j < L_SEQ; ++j) {
      float p = sc[tid][j];
#pragma unroll
      for (int d2 = 0; d2 < HD; ++d2) oacc[d2] += p * v_s[j][d2];
    }
    float* op = o + (rowbase + tid) * D + h * HD;
#pragma unroll
    for (int d2 = 0; d2 < HD; ++d2) op[d2] = oacc[d2] * inv;
  }
}

__global__ __launch_bounds__(128) void out_mean_kernel(
    const float* __restrict__ o, const float* __restrict__ Wo,
    const float* __restrict__ bo, float* __restrict__ out, int L) {
  __shared__ float m_s[D];
  int b = blockIdx.x, tid = threadIdx.x;
  float s = 0.f;
  for (int l = 0; l < L; ++l) s += o[((size_t)b * L + l) * D + tid];
  m_s[tid] = s / (float)L;
  __syncthreads();
  const float4* w4 = reinterpret_cast<const float4*>(Wo + (size_t)tid * D);
  float acc = 0.f;
  for (int k4 = 0; k4 < D / 4; ++k4) {
    float4 w = w4[k4];
    int k = k4 * 4;
    acc += m_s[k] * w.x + m_s[k + 1] * w.y + m_s[k + 2] * w.z + m_s[k + 3] * w.w;
  }
  out[(size_t)b * D + tid] = acc + bo[tid];
}

// ---------------- launch ----------------

extern "C" void kernel_launch(void* const* d_in, const int* in_sizes, int n_in,
                              void* d_out, int out_size, void* d_ws, size_t ws_size,
                              hipStream_t stream) {
  const float* embeds   = (const float*)d_in[0];
  const float* gcn_W    = (const float*)d_in[1];
  const float* gcn_b    = (const float*)d_in[2];
  const float* in_w     = (const float*)d_in[3];
  const float* in_b     = (const float*)d_in[4];
  const float* out_w    = (const float*)d_in[5];
  const float* out_b    = (const float*)d_in[6];
  const float* dist_vec = (const float*)d_in[7];
  const int*   edges    = (const int*)d_in[8];
  const int*   x_idx    = (const int*)d_in[9];
  const int*   poi_idx  = (const int*)d_in[10];
  float* out = (float*)d_out;

  int N  = in_sizes[0] / D;   // 50000
  int E  = in_sizes[7];       // 400000
  int BL = in_sizes[9];       // 6400
  int B  = in_sizes[10];      // 64
  int L  = BL / B;            // 100
  const int* e0 = edges;
  const int* e1 = edges + E;
  size_t total_edges = (size_t)2 * E + N;          // 850000
  int Npad = ((N + 127) / 128) * 128;              // 50048
  int NB   = (N + 1023) / 1024;                    // 49 (<= 64)

  char* p = (char*)d_ws;
  auto alloc = [&](size_t bytes) { char* q = p; p += (bytes + 255) & ~(size_t)255; return q; };
  int*   deg       = (int*)alloc((size_t)N * 4);
  int*   row_ptr   = (int*)alloc((size_t)(N + 1) * 4);
  int*   cursor    = (int*)alloc((size_t)N * 4);
  int*   bsum      = (int*)alloc((size_t)NB * 4);
  int*   chunk_ctr = (int*)alloc((size_t)SC_BUCKETS * 4);
  uint2* ecw       = (uint2*)alloc(total_edges * 8);
  unsigned short* emb_bf = (unsigned short*)alloc((size_t)Npad * D * 2);
  unsigned short* W_bf   = (unsigned short*)alloc((size_t)GCN_NUM * D * D * 2);
  unsigned short* inw_bf = (unsigned short*)alloc((size_t)3 * D * D * 2);
  unsigned short* agg_bf = (unsigned short*)alloc((size_t)Npad * D * 2);
  unsigned short* enc_bf = (unsigned short*)alloc((size_t)Npad * D * 2);
  float* qkv  = (float*)alloc((size_t)BL * 384 * 4);
  float* obuf = (float*)alloc((size_t)BL * D * 4);

  // fused converts + deg init + chunk-counter zero
  int n4e = N * D / 4, n4w = GCN_NUM * D * D / 4, n4i = 3 * D * D / 4;
  int prep_tot = n4e + n4w + n4i + N;
  prep<<<(prep_tot + 255) / 256, 256, 0, stream>>>(
      embeds, emb_bf, n4e, gcn_W, W_bf, n4w, in_w, inw_bf, n4i, deg, N, chunk_ctr);

  // graph build
  count_deg<<<1024, 256, 0, stream>>>(e0, e1, deg, E);
  block_sum<<<NB, 1024, 0, stream>>>(deg, bsum, N);
  scan_final<<<NB, 1024, 0, stream>>>(deg, bsum, row_ptr, cursor, N, NB);
  int span = (N + SC_BUCKETS - 1) / SC_BUCKETS;
  scatter_edges_xcc<<<2048, 256, 0, stream>>>(
      e0, e1, dist_vec, deg, cursor, chunk_ctr, ecw, E, N, span);

  // GCN layers (bf16 storage, MFMA dense)
  const unsigned short* cur_in = emb_bf;
  for (int i = 0; i < GCN_NUM; ++i) {
    spmm_bf<<<(N + 3) / 4, 256, 0, stream>>>(row_ptr, ecw, cur_in, agg_bf, N);
    dense_mfma<<<Npad / 128, 256, 0, stream>>>(
        agg_bf, W_bf + (size_t)i * D * D, gcn_b + (size_t)i * D, enc_bf, N);
    cur_in = enc_bf;
  }

  // gathers + attention
  gather_tar<<<B, 64, 0, stream>>>(enc_bf, poi_idx, out + (size_t)B * D, B);
  dim3 qgrid(BL / 128, 3);
  qkv_mfma<<<qgrid, 256, 0, stream>>>(enc_bf, x_idx, inw_bf, in_b, qkv, BL);
  attn_kernel<<<B * HEADS, 128, 0, stream>>>(qkv, obuf);
  out_mean_kernel<<<B, 128, 0, stream>>>(obuf, out_w, out_b, out, L);
}

// Round 9
// 358.095 us; speedup vs baseline: 1.1412x; 1.1412x over previous
//
#include <hip/hip_runtime.h>
#include <math.h>

#define D 128
#define GCN_NUM 3
#define HEADS 8
#define HD 16
#define L_SEQ 100
#define LEAKY 0.01f
#define SC_BUCKETS 8

typedef __attribute__((ext_vector_type(8))) short short8v;
typedef __attribute__((ext_vector_type(4))) float f32x4;

__device__ __forceinline__ unsigned f2bf(float x) {
  unsigned u = __float_as_uint(x);
  return (u + 0x7FFFu + ((u >> 16) & 1u)) >> 16;
}
__device__ __forceinline__ float bflo2f(unsigned u) { return __uint_as_float(u << 16); }
__device__ __forceinline__ float bfhi2f(unsigned u) { return __uint_as_float(u & 0xFFFF0000u); }

// ---------------- prep: fused f32->bf16 converts + deg init ----------------

__global__ void prep(const float* __restrict__ s0, unsigned short* __restrict__ d0, int n0,
                     const float* __restrict__ s1, unsigned short* __restrict__ d1, int n1,
                     const float* __restrict__ s2, unsigned short* __restrict__ d2, int n2,
                     int* __restrict__ deg, int N) {
  int i = blockIdx.x * blockDim.x + threadIdx.x;
  int n4tot = n0 + n1 + n2;
  if (i < n4tot) {
    const float* s; unsigned short* d; int j;
    if (i < n0)           { s = s0; d = d0; j = i; }
    else if (i < n0 + n1) { s = s1; d = d1; j = i - n0; }
    else                  { s = s2; d = d2; j = i - n0 - n1; }
    float4 v = reinterpret_cast<const float4*>(s)[j];
    uint2 o;
    o.x = f2bf(v.x) | (f2bf(v.y) << 16);
    o.y = f2bf(v.z) | (f2bf(v.w) << 16);
    reinterpret_cast<uint2*>(d)[j] = o;
  } else if (i - n4tot < N) {
    deg[i - n4tot] = 1;  // self-loop
  }
}

// ---------------- graph build ----------------

__global__ void count_deg(const int* __restrict__ e0, const int* __restrict__ e1,
                          int* __restrict__ deg, int E) {
  int stride = gridDim.x * blockDim.x;
  for (int i = blockIdx.x * blockDim.x + threadIdx.x; i < E; i += stride) {
    atomicAdd(&deg[e0[i]], 1);
    atomicAdd(&deg[e1[i]], 1);
  }
}

// ---- parallel exclusive scan over deg (2 kernels; NB <= 64) ----

__global__ __launch_bounds__(1024) void block_sum(const int* __restrict__ deg,
                                                  int* __restrict__ bsum, int n) {
  __shared__ int ws[16];
  int tid = threadIdx.x, lane = tid & 63, wid = tid >> 6;
  int i = blockIdx.x * 1024 + tid;
  int v = (i < n) ? deg[i] : 0;
#pragma unroll
  for (int off = 32; off; off >>= 1) v += __shfl_xor(v, off);
  if (lane == 0) ws[wid] = v;
  __syncthreads();
  if (tid == 0) {
    int s = 0;
#pragma unroll
    for (int k = 0; k < 16; ++k) s += ws[k];
    bsum[blockIdx.x] = s;
  }
}

__global__ __launch_bounds__(1024) void scan_final(
    const int* __restrict__ deg, const int* __restrict__ bsum,
    int* __restrict__ row_ptr, int* __restrict__ cursor, int n, int nb) {
  __shared__ int ws[16];
  __shared__ int prefix_s;
  int tid = threadIdx.x, lane = tid & 63, wid = tid >> 6;
  int i = blockIdx.x * 1024 + tid;
  int v = (i < n) ? deg[i] : 0;
  int x = v;
#pragma unroll
  for (int off = 1; off < 64; off <<= 1) {
    int y = __shfl_up(x, off);
    if (lane >= off) x += y;
  }
  if (lane == 63) ws[wid] = x;
  __syncthreads();
  if (wid == 0) {
    int pv = (lane < blockIdx.x) ? bsum[lane] : 0;
#pragma unroll
    for (int off = 32; off; off >>= 1) pv += __shfl_xor(pv, off);
    if (lane == 0) prefix_s = pv;
    int s = (lane < 16) ? ws[lane] : 0;
#pragma unroll
    for (int off = 1; off < 16; off <<= 1) {
      int y = __shfl_up(s, off);
      if (lane >= off) s += y;
    }
    if (lane < 16) ws[lane] = s;
  }
  __syncthreads();
  int woff = wid ? ws[wid - 1] : 0;
  int prefix = prefix_s;
  if (i < n) {
    int pval = prefix + woff + (x - v);
    row_ptr[i] = pval;
    cursor[i] = pval;
  }
  if (blockIdx.x == nb - 1 && tid == 0) row_ptr[n] = prefix + ws[15];
}

// bucketed scatter (round-7 structure), 4-byte packed descriptor:
// desc = col(u16, N<65536) | bf16(w) << 16. Halves random-store bytes.
__global__ __launch_bounds__(256) void scatter_edges_p(
    const int* __restrict__ e0, const int* __restrict__ e1,
    const float* __restrict__ dv, const int* __restrict__ deg,
    int* __restrict__ cursor, unsigned* __restrict__ ecw,
    int E, int N, int span, int bpb) {
  int bucket = blockIdx.x & (SC_BUCKETS - 1);
  int bx = blockIdx.x >> 3;
  int rlo = bucket * span;
  int rhi = min(rlo + span, N);
  int total = 2 * E + N;
  int stride = bpb * 256;
  for (int i = bx * 256 + threadIdx.x; i < total; i += stride) {
    int r, c; bool self = false;
    if (i < E)          { r = e0[i];     c = e1[i]; }
    else if (i < 2 * E) { r = e1[i - E]; c = e0[i - E]; }
    else                { r = i - 2 * E; c = r; self = true; }
    if (r < rlo || r >= rhi) continue;
    float d = self ? 0.f : dv[(i < E) ? i : i - E];
    float w = expf(-d * d) * (1.0f / sqrtf((float)deg[r])) * (1.0f / sqrtf((float)deg[c]));
    int pos = atomicAdd(&cursor[r], 1);
    ecw[pos] = (unsigned)c | (f2bf(w) << 16);
  }
}

// ---------------- GCN ----------------

// SpMM: one row per wave, 4 edge-groups of 16 lanes, 3-deep pipeline per group
// (3 row gathers + 3 descriptor prefetches in flight -> 12 gathers/wave).
__global__ __launch_bounds__(256) void spmm_bf(
    const int* __restrict__ row_ptr, const unsigned* __restrict__ ecw,
    const unsigned short* __restrict__ enc, unsigned short* __restrict__ agg, int n) {
  int r = blockIdx.x * 4 + (threadIdx.x >> 6);
  if (r >= n) return;
  int lane = threadIdx.x & 63;
  int g = lane >> 4, t = lane & 15;
  int s = row_ptr[r], e = row_ptr[r + 1];
  float a0 = 0.f, a1 = 0.f, a2 = 0.f, a3 = 0.f, a4 = 0.f, a5 = 0.f, a6 = 0.f, a7 = 0.f;
  int i = s + g;  // this group's edges: i, i+4, i+8, ...
  unsigned dA = 0u, dB = 0u, dC = 0u;
  if (i < e)     dA = ecw[i];
  if (i + 4 < e) dB = ecw[i + 4];
  if (i + 8 < e) dC = ecw[i + 8];
  while (i + 8 < e) {
    unsigned nA = dA, nB = dB, nC = dC;
    if (i + 12 < e) nA = ecw[i + 12];
    if (i + 16 < e) nB = ecw[i + 16];
    if (i + 20 < e) nC = ecw[i + 20];
    float wA = bfhi2f(dA), wB = bfhi2f(dB), wC = bfhi2f(dC);
    uint4 uA = *reinterpret_cast<const uint4*>(enc + (size_t)(dA & 0xFFFFu) * D + t * 8);
    uint4 uB = *reinterpret_cast<const uint4*>(enc + (size_t)(dB & 0xFFFFu) * D + t * 8);
    uint4 uC = *reinterpret_cast<const uint4*>(enc + (size_t)(dC & 0xFFFFu) * D + t * 8);
    a0 = fmaf(wA, bflo2f(uA.x), a0); a1 = fmaf(wA, bfhi2f(uA.x), a1);
    a2 = fmaf(wA, bflo2f(uA.y), a2); a3 = fmaf(wA, bfhi2f(uA.y), a3);
    a4 = fmaf(wA, bflo2f(uA.z), a4); a5 = fmaf(wA, bfhi2f(uA.z), a5);
    a6 = fmaf(wA, bflo2f(uA.w), a6); a7 = fmaf(wA, bfhi2f(uA.w), a7);
    a0 = fmaf(wB, bflo2f(uB.x), a0); a1 = fmaf(wB, bfhi2f(uB.x), a1);
    a2 = fmaf(wB, bflo2f(uB.y), a2); a3 = fmaf(wB, bfhi2f(uB.y), a3);
    a4 = fmaf(wB, bflo2f(uB.z), a4); a5 = fmaf(wB, bfhi2f(uB.z), a5);
    a6 = fmaf(wB, bflo2f(uB.w), a6); a7 = fmaf(wB, bfhi2f(uB.w), a7);
    a0 = fmaf(wC, bflo2f(uC.x), a0); a1 = fmaf(wC, bfhi2f(uC.x), a1);
    a2 = fmaf(wC, bflo2f(uC.y), a2); a3 = fmaf(wC, bfhi2f(uC.y), a3);
    a4 = fmaf(wC, bflo2f(uC.z), a4); a5 = fmaf(wC, bfhi2f(uC.z), a5);
    a6 = fmaf(wC, bflo2f(uC.w), a6); a7 = fmaf(wC, bfhi2f(uC.w), a7);
    dA = nA; dB = nB; dC = nC;
    i += 12;
  }
  // tail: up to 2 edges left for this group (descs already loaded)
  if (i < e) {
    float wA = bfhi2f(dA);
    uint4 uA = *reinterpret_cast<const uint4*>(enc + (size_t)(dA & 0xFFFFu) * D + t * 8);
    a0 = fmaf(wA, bflo2f(uA.x), a0); a1 = fmaf(wA, bfhi2f(uA.x), a1);
    a2 = fmaf(wA, bflo2f(uA.y), a2); a3 = fmaf(wA, bfhi2f(uA.y), a3);
    a4 = fmaf(wA, bflo2f(uA.z), a4); a5 = fmaf(wA, bfhi2f(uA.z), a5);
    a6 = fmaf(wA, bflo2f(uA.w), a6); a7 = fmaf(wA, bfhi2f(uA.w), a7);
  }
  if (i + 4 < e) {
    float wB = bfhi2f(dB);
    uint4 uB = *reinterpret_cast<const uint4*>(enc + (size_t)(dB & 0xFFFFu) * D + t * 8);
    a0 = fmaf(wB, bflo2f(uB.x), a0); a1 = fmaf(wB, bfhi2f(uB.x), a1);
    a2 = fmaf(wB, bflo2f(uB.y), a2); a3 = fmaf(wB, bfhi2f(uB.y), a3);
    a4 = fmaf(wB, bflo2f(uB.z), a4); a5 = fmaf(wB, bfhi2f(uB.z), a5);
    a6 = fmaf(wB, bflo2f(uB.w), a6); a7 = fmaf(wB, bfhi2f(uB.w), a7);
  }
  a0 += __shfl_xor(a0, 16); a0 += __shfl_xor(a0, 32);
  a1 += __shfl_xor(a1, 16); a1 += __shfl_xor(a1, 32);
  a2 += __shfl_xor(a2, 16); a2 += __shfl_xor(a2, 32);
  a3 += __shfl_xor(a3, 16); a3 += __shfl_xor(a3, 32);
  a4 += __shfl_xor(a4, 16); a4 += __shfl_xor(a4, 32);
  a5 += __shfl_xor(a5, 16); a5 += __shfl_xor(a5, 32);
  a6 += __shfl_xor(a6, 16); a6 += __shfl_xor(a6, 32);
  a7 += __shfl_xor(a7, 16); a7 += __shfl_xor(a7, 32);
  if (g == 0) {
    uint4 o;
    o.x = f2bf(a0) | (f2bf(a1) << 16);
    o.y = f2bf(a2) | (f2bf(a3) << 16);
    o.z = f2bf(a4) | (f2bf(a5) << 16);
    o.w = f2bf(a6) | (f2bf(a7) << 16);
    *reinterpret_cast<uint4*>(agg + (size_t)r * D + t * 8) = o;
  }
}

// enc = normalize(leaky_relu(A @ W^T + b)) via MFMA bf16.
__global__ __launch_bounds__(256) void dense_mfma(
    const unsigned short* __restrict__ A, const unsigned short* __restrict__ Wb,
    const float* __restrict__ bias, unsigned short* __restrict__ enc, int n) {
  __shared__ unsigned short Wl[128 * 136];
  int tid = threadIdx.x;
  {
    int cg = (tid & 15) * 8;
    int r0 = tid >> 4;
#pragma unroll
    for (int i = 0; i < 8; ++i) {
      int row = r0 + i * 16;
      *reinterpret_cast<short8v*>(&Wl[row * 136 + cg]) =
          *reinterpret_cast<const short8v*>(Wb + row * D + cg);
    }
  }
  __syncthreads();
  int w = tid >> 6, lane = tid & 63;
  int lr = lane & 15, lg = lane >> 4;
#pragma unroll
  for (int rt = 0; rt < 2; ++rt) {
    int rbase = blockIdx.x * 128 + rt * 64 + w * 16;
    f32x4 acc[8];
#pragma unroll
    for (int j = 0; j < 8; ++j) acc[j] = f32x4{0.f, 0.f, 0.f, 0.f};
    const unsigned short* arow = A + (size_t)(rbase + lr) * D + lg * 8;
#pragma unroll
    for (int ks = 0; ks < 4; ++ks) {
      short8v a = *reinterpret_cast<const short8v*>(arow + ks * 32);
#pragma unroll
      for (int jt = 0; jt < 8; ++jt) {
        short8v b = *reinterpret_cast<const short8v*>(&Wl[(jt * 16 + lr) * 136 + ks * 32 + lg * 8]);
        acc[jt] = __builtin_amdgcn_mfma_f32_16x16x32_bf16(a, b, acc[jt], 0, 0, 0);
      }
    }
    float vals[8][4];
    float ss[4] = {0.f, 0.f, 0.f, 0.f};
#pragma unroll
    for (int jt = 0; jt < 8; ++jt) {
      float bj = bias[jt * 16 + lr];
#pragma unroll
      for (int i = 0; i < 4; ++i) {
        float t = acc[jt][i] + bj;
        t = (t > 0.f) ? t : LEAKY * t;
        vals[jt][i] = t;
        ss[i] += t * t;
      }
    }
#pragma unroll
    for (int i = 0; i < 4; ++i) {
      float s = ss[i];
      s += __shfl_xor(s, 1); s += __shfl_xor(s, 2);
      s += __shfl_xor(s, 4); s += __shfl_xor(s, 8);
      ss[i] = 1.0f / fmaxf(sqrtf(s), 1e-12f);
    }
#pragma unroll
    for (int i = 0; i < 4; ++i) {
      int row = rbase + lg * 4 + i;
      if (row < n) {
#pragma unroll
        for (int jt = 0; jt < 8; ++jt)
          enc[(size_t)row * D + jt * 16 + lr] = (unsigned short)f2bf(vals[jt][i] * ss[i]);
      }
    }
  }
}

// ---------------- gather + attention ----------------

__global__ void gather_tar(const unsigned short* __restrict__ src,
                           const int* __restrict__ poi_idx, float* __restrict__ tar, int B) {
  int j = blockIdx.x;
  if (j < B) {
    int t = threadIdx.x;  // 64 threads
    unsigned u = reinterpret_cast<const unsigned*>(src + (size_t)poi_idx[j] * D)[t];
    reinterpret_cast<float2*>(tar + (size_t)j * D)[t] = make_float2(bflo2f(u), bfhi2f(u));
  }
}

// qkv via MFMA with fused x_idx row gather: A row = enc[x_idx[row]].
__global__ __launch_bounds__(256) void qkv_mfma(
    const unsigned short* __restrict__ enc, const int* __restrict__ x_idx,
    const unsigned short* __restrict__ Wb, const float* __restrict__ bias,
    float* __restrict__ qkv, int M) {
  __shared__ unsigned short Wl[128 * 136];
  int tid = threadIdx.x;
  const unsigned short* Wslab = Wb + (size_t)blockIdx.y * 128 * D;
  {
    int cg = (tid & 15) * 8;
    int r0 = tid >> 4;
#pragma unroll
    for (int i = 0; i < 8; ++i) {
      int row = r0 + i * 16;
      *reinterpret_cast<short8v*>(&Wl[row * 136 + cg]) =
          *reinterpret_cast<const short8v*>(Wslab + row * D + cg);
    }
  }
  __syncthreads();
  int w = tid >> 6, lane = tid & 63;
  int lr = lane & 15, lg = lane >> 4;
  int colbase = blockIdx.y * 128;
#pragma unroll
  for (int rt = 0; rt < 2; ++rt) {
    int rbase = blockIdx.x * 128 + rt * 64 + w * 16;
    f32x4 acc[8];
#pragma unroll
    for (int j = 0; j < 8; ++j) acc[j] = f32x4{0.f, 0.f, 0.f, 0.f};
    const unsigned short* arow = enc + (size_t)x_idx[rbase + lr] * D + lg * 8;
#pragma unroll
    for (int ks = 0; ks < 4; ++ks) {
      short8v a = *reinterpret_cast<const short8v*>(arow + ks * 32);
#pragma unroll
      for (int jt = 0; jt < 8; ++jt) {
        short8v b = *reinterpret_cast<const short8v*>(&Wl[(jt * 16 + lr) * 136 + ks * 32 + lg * 8]);
        acc[jt] = __builtin_amdgcn_mfma_f32_16x16x32_bf16(a, b, acc[jt], 0, 0, 0);
      }
    }
#pragma unroll
    for (int jt = 0; jt < 8; ++jt) {
      int j = colbase + jt * 16 + lr;
      float bj = bias[j];
#pragma unroll
      for (int i = 0; i < 4; ++i) {
        int row = rbase + lg * 4 + i;
        if (row < M) qkv[(size_t)row * 384 + j] = acc[jt][i] + bj;
      }
    }
  }
}

__global__ __launch_bounds__(128) void attn_kernel(
    const float* __restrict__ qkv, float* __restrict__ o) {
  __shared__ float k_s[L_SEQ][HD];
  __shared__ float v_s[L_SEQ][HD];
  __shared__ float sc[L_SEQ][L_SEQ + 1];
  int b = blockIdx.x / HEADS;
  int h = blockIdx.x % HEADS;
  int tid = threadIdx.x;
  const size_t rowbase = (size_t)b * L_SEQ;
  for (int idx = tid; idx < L_SEQ * HD; idx += 128) {
    int l = idx >> 4, d2 = idx & 15;
    const float* base = qkv + (rowbase + l) * 384 + h * HD + d2;
    k_s[l][d2] = base[128];
    v_s[l][d2] = base[256];
  }
  __syncthreads();
  if (tid < L_SEQ) {
    float q[HD];
    const float* qp = qkv + (rowbase + tid) * 384 + h * HD;
#pragma unroll
    for (int d2 = 0; d2 < HD; ++d2) q[d2] = qp[d2];
    float m = -1e30f;
    for (int j = 0; j < L_SEQ; ++j) {
      float s = 0.f;
#pragma unroll
      for (int d2 = 0; d2 < HD; ++d2) s += q[d2] * k_s[j][d2];
      s *= 0.25f;
      sc[tid][j] = s;
      m = fmaxf(m, s);
    }
    float sum = 0.f;
    for (int j = 0; j < L_SEQ; ++j) {
      float e = expf(sc[tid][j] - m);
      sc[tid][j] = e;
      sum += e;
    }
    float inv = 1.f / sum;
    float oacc[HD];
#pragma unroll
    for (int d2 = 0; d2 < HD; ++d2) oacc[d2] = 0.f;
    for (int j = 0; j < L_SEQ; ++j) {
      float p = sc[tid][j];
#pragma unroll
      for (int d2 = 0; d2 < HD; ++d2) oacc[d2] += p * v_s[j][d2];
    }
    float* op = o + (rowbase + tid) * D + h * HD;
#pragma unroll
    for (int d2 = 0; d2 < HD; ++d2) op[d2] = oacc[d2] * inv;
  }
}

__global__ __launch_bounds__(128) void out_mean_kernel(
    const float* __restrict__ o, const float* __restrict__ Wo,
    const float* __restrict__ bo, float* __restrict__ out, int L) {
  __shared__ float m_s[D];
  int b = blockIdx.x, tid = threadIdx.x;
  float s = 0.f;
  for (int l = 0; l < L; ++l) s += o[((size_t)b * L + l) * D + tid];
  m_s[tid] = s / (float)L;
  __syncthreads();
  const float4* w4 = reinterpret_cast<const float4*>(Wo + (size_t)tid * D);
  float acc = 0.f;
  for (int k4 = 0; k4 < D / 4; ++k4) {
    float4 w = w4[k4];
    int k = k4 * 4;
    acc += m_s[k] * w.x + m_s[k + 1] * w.y + m_s[k + 2] * w.z + m_s[k + 3] * w.w;
  }
  out[(size_t)b * D + tid] = acc + bo[tid];
}

// ---------------- launch ----------------

extern "C" void kernel_launch(void* const* d_in, const int* in_sizes, int n_in,
                              void* d_out, int out_size, void* d_ws, size_t ws_size,
                              hipStream_t stream) {
  const float* embeds   = (const float*)d_in[0];
  const float* gcn_W    = (const float*)d_in[1];
  const float* gcn_b    = (const float*)d_in[2];
  const float* in_w     = (const float*)d_in[3];
  const float* in_b     = (const float*)d_in[4];
  const float* out_w    = (const float*)d_in[5];
  const float* out_b    = (const float*)d_in[6];
  const float* dist_vec = (const float*)d_in[7];
  const int*   edges    = (const int*)d_in[8];
  const int*   x_idx    = (const int*)d_in[9];
  const int*   poi_idx  = (const int*)d_in[10];
  float* out = (float*)d_out;

  int N  = in_sizes[0] / D;   // 50000
  int E  = in_sizes[7];       // 400000
  int BL = in_sizes[9];       // 6400
  int B  = in_sizes[10];      // 64
  int L  = BL / B;            // 100
  const int* e0 = edges;
  const int* e1 = edges + E;
  size_t total_edges = (size_t)2 * E + N;          // 850000
  int Npad = ((N + 127) / 128) * 128;              // 50048
  int NB   = (N + 1023) / 1024;                    // 49 (<= 64)

  char* p = (char*)d_ws;
  auto alloc = [&](size_t bytes) { char* q = p; p += (bytes + 255) & ~(size_t)255; return q; };
  int*      deg     = (int*)alloc((size_t)N * 4);
  int*      row_ptr = (int*)alloc((size_t)(N + 1) * 4);
  int*      cursor  = (int*)alloc((size_t)N * 4);
  int*      bsum    = (int*)alloc((size_t)NB * 4);
  unsigned* ecw     = (unsigned*)alloc(total_edges * 4);
  unsigned short* emb_bf = (unsigned short*)alloc((size_t)Npad * D * 2);
  unsigned short* W_bf   = (unsigned short*)alloc((size_t)GCN_NUM * D * D * 2);
  unsigned short* inw_bf = (unsigned short*)alloc((size_t)3 * D * D * 2);
  unsigned short* agg_bf = (unsigned short*)alloc((size_t)Npad * D * 2);
  unsigned short* enc_bf = (unsigned short*)alloc((size_t)Npad * D * 2);
  float* qkv  = (float*)alloc((size_t)BL * 384 * 4);
  float* obuf = (float*)alloc((size_t)BL * D * 4);

  // fused converts + deg init
  int n4e = N * D / 4, n4w = GCN_NUM * D * D / 4, n4i = 3 * D * D / 4;
  int prep_tot = n4e + n4w + n4i + N;
  prep<<<(prep_tot + 255) / 256, 256, 0, stream>>>(
      embeds, emb_bf, n4e, gcn_W, W_bf, n4w, in_w, inw_bf, n4i, deg, N);

  // graph build
  count_deg<<<1024, 256, 0, stream>>>(e0, e1, deg, E);
  block_sum<<<NB, 1024, 0, stream>>>(deg, bsum, N);
  scan_final<<<NB, 1024, 0, stream>>>(deg, bsum, row_ptr, cursor, N, NB);
  int span = (N + SC_BUCKETS - 1) / SC_BUCKETS;
  int bpb = 512;
  scatter_edges_p<<<SC_BUCKETS * bpb, 256, 0, stream>>>(
      e0, e1, dist_vec, deg, cursor, ecw, E, N, span, bpb);

  // GCN layers (bf16 storage, MFMA dense)
  const unsigned short* cur_in = emb_bf;
  for (int i = 0; i < GCN_NUM; ++i) {
    spmm_bf<<<(N + 3) / 4, 256, 0, stream>>>(row_ptr, ecw, cur_in, agg_bf, N);
    dense_mfma<<<Npad / 128, 256, 0, stream>>>(
        agg_bf, W_bf + (size_t)i * D * D, gcn_b + (size_t)i * D, enc_bf, N);
    cur_in = enc_bf;
  }

  // gathers + attention
  gather_tar<<<B, 64, 0, stream>>>(enc_bf, poi_idx, out + (size_t)B * D, B);
  dim3 qgrid(BL / 128, 3);
  qkv_mfma<<<qgrid, 256, 0, stream>>>(enc_bf, x_idx, inw_bf, in_b, qkv, BL);
  attn_kernel<<<B * HEADS, 128, 0, stream>>>(qkv, obuf);
  out_mean_kernel<<<B, 128, 0, stream>>>(obuf, out_w, out_b, out, L);
}